// Round 3
// 626.421 us; speedup vs baseline: 1.0468x; 1.0468x over previous
//
#include <hip/hip_runtime.h>

#define NBINS 20
#define C 128

// clang-native vector type: required by __builtin_nontemporal_load
// (HIP_vector_type float4 is a struct and is rejected).
typedef float vf4 __attribute__((ext_vector_type(4)));

// ws layout: double csum[20] | unsigned cnt[20] | unsigned cor[20]  (320 B)
// NOTE: the harness re-poisons the FULL ws (2 GB) before every timed launch —
// that fill is ~318 us at write-roofline and is a fixed floor we don't control.

// pass1: 8 lanes/row, 4 vf4 loads/lane per row, 8-row half-steps, register
// double-buffered so the next half-step's 5 loads (4x vf4 + label) are in
// flight across the current half-step's scan/shfl/atomic tail.
__global__ __launch_bounds__(256) void ece_pass1(
    const float* __restrict__ sm, const int* __restrict__ labels, int N,
    double* __restrict__ g_csum, unsigned* __restrict__ g_cnt,
    unsigned* __restrict__ g_cor) {
  __shared__ float s_csum[NBINS];
  __shared__ unsigned s_cc[NBINS];  // cnt in [15:0] | cor in [31:16]
  const int tid = threadIdx.x;
  if (tid < NBINS) { s_csum[tid] = 0.f; s_cc[tid] = 0u; }
  __syncthreads();

  const int lane = tid & 63;
  const int p = lane & 7;   // position within row (8 lanes/row)
  const int r = lane >> 3;  // row within the 8-row half-step

  const long long gw   = (long long)blockIdx.x * 4 + (tid >> 6);
  const long long hstr = (long long)gridDim.x * 4 * 2;  // half-steps per sweep
  const long long nh   = ((long long)N + 7) >> 3;

  vf4 va[4], vb[4];
  int la = 0, lb = 0;

  // Issue the 4 tile loads + label load for half-step hh into (v, lab).
  // Whole 8-lane group shares one row -> row<N is wave-group-uniform.
  auto issue = [&](long long hh, vf4 (&v)[4], int& lab) {
    const long long row = hh * 8 + r;
    if (row < (long long)N) {
      const vf4* rp = (const vf4*)(sm + row * (long long)C);
#pragma unroll
      for (int k = 0; k < 4; ++k)
        v[k] = __builtin_nontemporal_load(rp + p + k * 8);  // one-shot stream
      lab = labels[row];  // 8 distinct dwords/wave, contiguous 32 B
    } else {
#pragma unroll
      for (int k = 0; k < 4; ++k) v[k] = (vf4){-2.f, -2.f, -2.f, -2.f};
      lab = -1;
    }
  };

  // In-lane argmax over 16 values (ascending flat index, strict '>' keeps the
  // first occurrence = jnp.argmax tie-break), then 8-lane xor reduce, then
  // leader lane does 2 LDS atomics (csum float + packed cnt|cor).
  auto process = [&](long long hh, const vf4 (&v)[4], int lab) {
    float bv = -3.f;
    int bi = 0;
#pragma unroll
    for (int k = 0; k < 4; ++k) {
      const vf4 q = v[k];
      const int b0 = k * 32 + p * 4;
      if (q.x > bv) { bv = q.x; bi = b0; }
      if (q.y > bv) { bv = q.y; bi = b0 + 1; }
      if (q.z > bv) { bv = q.z; bi = b0 + 2; }
      if (q.w > bv) { bv = q.w; bi = b0 + 3; }
    }
#pragma unroll
    for (int off = 1; off <= 4; off <<= 1) {
      const float ov = __shfl_xor(bv, off);
      const int   oi = __shfl_xor(bi, off);
      if (ov > bv || (ov == bv && oi < bi)) { bv = ov; bi = oi; }
    }
    const long long row = hh * 8 + r;
    if (p == 0 && row < (long long)N) {
      int bin = (int)ceilf(bv * 20.0f) - 1;  // matches jnp.ceil(conf*20)-1
      bin = min(max(bin, 0), NBINS - 1);
      atomicAdd(&s_csum[bin], bv);
      // per-block rows <= 512 << 2^16 at grid=2048 -> packed add is safe
      atomicAdd(&s_cc[bin], 1u + ((bi == lab) ? 0x10000u : 0u));
    }
  };

  // Half-step sequence per wave: gw*2, gw*2+1, then +hstr (same row coverage
  // as the previous 16-row iteration scheme).
  long long h = gw * 2;
  long long hn = h + 1;  // successor of an even half-step
  issue(h, va, la);

  while (h < nh) {
    issue(hn, vb, lb);   // prefetch: 5 loads in flight across process()
    process(h, va, la);
    h = hn;
    hn = (h & 1) ? (h + hstr - 1) : (h + 1);
    if (h >= nh) break;
    issue(hn, va, la);
    process(h, vb, lb);
    h = hn;
    hn = (h & 1) ? (h + hstr - 1) : (h + 1);
  }

  __syncthreads();
  if (tid < NBINS) {
    const unsigned cc = s_cc[tid];
    if (cc) {
      atomicAdd(&g_cnt[tid], cc & 0xFFFFu);
      atomicAdd(&g_cor[tid], cc >> 16);
      atomicAdd(&g_csum[tid], (double)s_csum[tid]);
    }
  }
}

__global__ void ece_pass2(const double* __restrict__ g_csum,
                          const unsigned* __restrict__ g_cnt,
                          const unsigned* __restrict__ g_cor,
                          float* __restrict__ out, int N) {
  const int i = threadIdx.x;
  double contrib = 0.0;
  if (i < NBINS) {
    const unsigned c = g_cnt[i];
    const double safe = c ? (double)c : 1.0;
    const double avg_conf = g_csum[i] / safe;
    const double avg_acc  = (double)g_cor[i] / safe;
    out[1 + i] = c ? (float)avg_acc : 0.f;  // ys
    if (c) contrib = fabs(avg_conf - avg_acc) * ((double)c / (double)N);
  }
#pragma unroll
  for (int off = 16; off >= 1; off >>= 1) contrib += __shfl_down(contrib, off);
  if (i == 0) out[0] = (float)contrib;  // ece
}

extern "C" void kernel_launch(void* const* d_in, const int* in_sizes, int n_in,
                              void* d_out, int out_size, void* d_ws, size_t ws_size,
                              hipStream_t stream) {
  const float* sm     = (const float*)d_in[0];
  const int*   labels = (const int*)d_in[1];
  const int N = in_sizes[1];  // labels count = number of rows

  double*   g_csum = (double*)d_ws;
  unsigned* g_cnt  = (unsigned*)((char*)d_ws + NBINS * sizeof(double));
  unsigned* g_cor  = g_cnt + NBINS;

  // ws is re-poisoned to 0xAA before every timed launch — zero accumulators.
  (void)hipMemsetAsync(d_ws, 0,
                       NBINS * sizeof(double) + 2 * NBINS * sizeof(unsigned),
                       stream);

  ece_pass1<<<2048, 256, 0, stream>>>(sm, labels, N, g_csum, g_cnt, g_cor);
  ece_pass2<<<1, 64, 0, stream>>>(g_csum, g_cnt, g_cor, (float*)d_out, N);
}